// Round 1
// baseline (301.396 us; speedup 1.0000x reference)
//
#include <hip/hip_runtime.h>
#include <math.h>

#define BATCH 256
#define FEAT 128
#define CAP 100000
#define HORIZON 24
#define NFEAT 7
#define ROWF (HORIZON*NFEAT)   // 168
#define K 5
#define CHUNK 200
#define NCHUNK 500             // CHUNK*NCHUNK == CAP exactly
#define NCAND (NCHUNK*K)       // 2500
#define CPT 10                 // ceil(NCAND/256)

// out layout (floats): retrieved [0,215040) | top_sims [215040,216320)
//                      valid_mask [216320,217600) | top_idx [217600,218880)
#define OUT_SIMS 215040
#define OUT_MASK 216320
#define OUT_IDX  217600

// ws layout (4-byte elems):
#define WS_QNT   0        // 128*256 floats
#define WS_SCALE 32768    // 100000 floats
#define WS_PSIM  132768   // NCHUNK*BATCH*K = 640000 floats
#define WS_PIDX  772768   // 640000 ints
// total 1,412,768 elems = 5.65 MB

__global__ __launch_bounds__(64) void qnorm_kernel(const float* __restrict__ q,
                                                   float* __restrict__ qnT) {
  int b = blockIdx.x;           // query row
  int l = threadIdx.x;          // lane 0..63, 2 dims each
  float2 v = reinterpret_cast<const float2*>(q + (size_t)b*FEAT)[l];
  float ss = v.x*v.x + v.y*v.y;
  #pragma unroll
  for (int o = 1; o < 64; o <<= 1) ss += __shfl_xor(ss, o);
  float inv = 1.0f / fmaxf(sqrtf(ss), 1e-12f);
  qnT[(2*l    )*BATCH + b] = v.x*inv;
  qnT[(2*l + 1)*BATCH + b] = v.y*inv;
}

__global__ __launch_bounds__(256) void kscale_kernel(const float* __restrict__ keys,
                                                     const int* __restrict__ ts,
                                                     const int* __restrict__ gstep,
                                                     float* __restrict__ scale) {
  int gid  = blockIdx.x*blockDim.x + threadIdx.x;
  int key  = gid >> 6;
  int lane = threadIdx.x & 63;
  if (key >= CAP) return;
  float2 v = reinterpret_cast<const float2*>(keys + (size_t)key*FEAT)[lane];
  float ss = v.x*v.x + v.y*v.y;
  #pragma unroll
  for (int o = 1; o < 64; o <<= 1) ss += __shfl_xor(ss, o);
  if (lane == 0) {
    float age = (float)(gstep[0] - ts[key]);
    float decay = powf(0.995f, age);
    scale[key] = decay / fmaxf(sqrtf(ss), 1e-12f);
  }
}

__global__ __launch_bounds__(256) void sim_topk_kernel(const float* __restrict__ keys,
                                                       const float* __restrict__ qnT,
                                                       const float* __restrict__ scale,
                                                       float* __restrict__ psim,
                                                       int* __restrict__ pidx) {
  int t = threadIdx.x;          // query index
  int chunk = blockIdx.x;
  int k0 = chunk * CHUNK;

  float qreg[FEAT];
  #pragma unroll
  for (int d = 0; d < FEAT; ++d) qreg[d] = qnT[d*BATCH + t];   // coalesced

  float s0=-INFINITY, s1=-INFINITY, s2=-INFINITY, s3=-INFINITY, s4=-INFINITY;
  int   i0=0, i1=0, i2=0, i3=0, i4=0;

  for (int k = k0; k < k0 + CHUNK; ++k) {
    // k is block-uniform -> compiler should scalarize these loads (s_load)
    const float4* kp = reinterpret_cast<const float4*>(keys + (size_t)k*FEAT);
    float a0=0.f, a1=0.f, a2=0.f, a3=0.f;
    #pragma unroll
    for (int d = 0; d < FEAT/4; ++d) {
      float4 kv = kp[d];
      a0 = fmaf(kv.x, qreg[4*d+0], a0);
      a1 = fmaf(kv.y, qreg[4*d+1], a1);
      a2 = fmaf(kv.z, qreg[4*d+2], a2);
      a3 = fmaf(kv.w, qreg[4*d+3], a3);
    }
    float sim = ((a0+a1)+(a2+a3)) * scale[k];
    // streaming ascending k + strict '>' == jax tie-break (lower idx first)
    if (sim > s4) {
      if (sim > s3) {
        s4=s3; i4=i3;
        if (sim > s2) {
          s3=s2; i3=i2;
          if (sim > s1) {
            s2=s1; i2=i1;
            if (sim > s0) { s1=s0; i1=i0; s0=sim; i0=k; }
            else          { s1=sim; i1=k; }
          } else { s2=sim; i2=k; }
        } else { s3=sim; i3=k; }
      } else { s4=sim; i4=k; }
    }
  }

  int base = (chunk*BATCH + t)*K;
  psim[base+0]=s0; psim[base+1]=s1; psim[base+2]=s2; psim[base+3]=s3; psim[base+4]=s4;
  pidx[base+0]=i0; pidx[base+1]=i1; pidx[base+2]=i2; pidx[base+3]=i3; pidx[base+4]=i4;
}

__global__ __launch_bounds__(256) void merge_kernel(const float* __restrict__ psim,
                                                    const int* __restrict__ pidx,
                                                    const float* __restrict__ values,
                                                    float* __restrict__ out) {
  int q = blockIdx.x;
  int t = threadIdx.x;

  float cs[CPT]; int ci[CPT];
  #pragma unroll
  for (int j = 0; j < CPT; ++j) {
    int c = t + j*256;
    if (c < NCAND) {
      int chunk = c / K, r = c % K;
      int a = (chunk*BATCH + q)*K + r;
      cs[j] = psim[a]; ci[j] = pidx[a];
    } else { cs[j] = -INFINITY; ci[j] = 0x7fffffff; }
  }

  __shared__ float lds_s[4];
  __shared__ int   lds_i[4];
  __shared__ float win_s;
  __shared__ int   win_i;

  unsigned taken = 0;
  for (int r = 0; r < K; ++r) {
    float bs = -INFINITY; int bi = 0x7fffffff;
    #pragma unroll
    for (int j = 0; j < CPT; ++j) {
      bool live = !((taken >> j) & 1u);
      bool bet  = live && (cs[j] > bs || (cs[j] == bs && ci[j] < bi));
      bs = bet ? cs[j] : bs;
      bi = bet ? ci[j] : bi;
    }
    #pragma unroll
    for (int o = 1; o < 64; o <<= 1) {
      float os = __shfl_xor(bs, o);
      int   oi = __shfl_xor(bi, o);
      if (os > bs || (os == bs && oi < bi)) { bs = os; bi = oi; }
    }
    int w = t >> 6;
    if ((t & 63) == 0) { lds_s[w] = bs; lds_i[w] = bi; }
    __syncthreads();
    if (t == 0) {
      float fs = lds_s[0]; int fi = lds_i[0];
      #pragma unroll
      for (int ww = 1; ww < 4; ++ww) {
        float os = lds_s[ww]; int oi = lds_i[ww];
        if (os > fs || (os == fs && oi < fi)) { fs = os; fi = oi; }
      }
      win_s = fs; win_i = fi;
      out[OUT_SIMS + q*K + r] = fs;
      out[OUT_MASK + q*K + r] = (fs >= 0.0f) ? 1.0f : 0.0f;
      out[OUT_IDX  + q*K + r] = (float)fi;
    }
    __syncthreads();
    float fs = win_s; int fi = win_i;
    #pragma unroll
    for (int j = 0; j < CPT; ++j) if (ci[j] == fi) taken |= (1u << j);
    for (int e = t; e < ROWF; e += 256)
      out[(q*K + r)*ROWF + e] = values[(size_t)fi*ROWF + e];
    __syncthreads();
  }
}

extern "C" void kernel_launch(void* const* d_in, const int* in_sizes, int n_in,
                              void* d_out, int out_size, void* d_ws, size_t ws_size,
                              hipStream_t stream) {
  const float* query  = (const float*)d_in[0];
  const float* keys   = (const float*)d_in[1];
  const float* values = (const float*)d_in[2];
  const int*   ts     = (const int*)d_in[3];
  const int*   gstep  = (const int*)d_in[4];
  // d_in[5] = top_k (=5), compile-time K

  float* out  = (float*)d_out;
  float* wsf  = (float*)d_ws;
  int*   wsi  = (int*)d_ws;

  float* qnT   = wsf + WS_QNT;
  float* scale = wsf + WS_SCALE;
  float* psim  = wsf + WS_PSIM;
  int*   pidx  = wsi + WS_PIDX;

  qnorm_kernel<<<BATCH, 64, 0, stream>>>(query, qnT);
  kscale_kernel<<<(CAP*64 + 255)/256, 256, 0, stream>>>(keys, ts, gstep, scale);
  sim_topk_kernel<<<NCHUNK, 256, 0, stream>>>(keys, qnT, scale, psim, pidx);
  merge_kernel<<<BATCH, 256, 0, stream>>>(psim, pidx, values, out);
}